// Round 2
// baseline (358.662 us; speedup 1.0000x reference)
//
#include <hip/hip_runtime.h>

// Problem constants (reference: T=128, L=32, C=4, B=32, D=512)
#define TT 128
#define LL 32
#define CC 4
#define BB 32
#define DD 512
#define D4 (DD / 4)   // 128 float4 per D-row

__device__ __forceinline__ float4 diff_scale(float4 a, float4 b, float s) {
    return make_float4((a.x - b.x) * s, (a.y - b.y) * s,
                       (a.z - b.z) * s, (a.w - b.w) * s);
}

// ---------------------------------------------------------------------------
// Kernel 1: inclusive prefix sum of f over t, per (b,d).
// P layout: [B][T+1][D], P[b][0][d]=0, P[b][t+1][d]=sum_{u<=t} f[b][u][d].
// One thread per (b,d); loads/stores coalesced across threads for each t.
// ---------------------------------------------------------------------------
__global__ __launch_bounds__(256) void prefix_kernel(const float* __restrict__ f,
                                                     float* __restrict__ P) {
    int idx = blockIdx.x * 256 + threadIdx.x;   // B*D threads
    int b = idx >> 9;                            // D = 512
    int d = idx & (DD - 1);
    const float* fp = f + (size_t)b * TT * DD + d;
    float* Pp = P + (size_t)b * (TT + 1) * DD + d;
    float acc = 0.f;
    Pp[0] = 0.f;
#pragma unroll 8
    for (int t = 0; t < TT; ++t) {
        acc += fp[(size_t)t * DD];
        Pp[(size_t)(t + 1) * DD] = acc;
    }
}

// ---------------------------------------------------------------------------
// Kernel 2: fc[b,i,j,c,:] and fm[b,i,j,:] from prefix sums. One block of 128
// threads per (b,i,j); thread = one float4 lane of D. j<i -> exact zeros.
// ---------------------------------------------------------------------------
__global__ __launch_bounds__(128) void fcfm_kernel(const float4* __restrict__ P4,
                                                   const float* __restrict__ mask,
                                                   float4* __restrict__ fc4,
                                                   float4* __restrict__ fm4) {
    int blk = blockIdx.x;            // b*L*L + i*L + j
    int j = blk & (LL - 1);
    int i = (blk >> 5) & (LL - 1);
    int b = blk >> 10;
    int tid = threadIdx.x;           // 0..127
    float4* fc_out = fc4 + (size_t)blk * CC * D4;
    float4* fm_out = fm4 + (size_t)blk * D4;

    if (j < i) {
        float4 z = make_float4(0.f, 0.f, 0.f, 0.f);
#pragma unroll
        for (int c = 0; c < CC; ++c) fc_out[c * D4 + tid] = z;
        fm_out[tid] = z;
        return;
    }

    int ws = j - i + 1;
    float sc = mask[blk] / (float)ws;
    float sm = 0.25f * sc;
    const float4* Pb = P4 + (size_t)b * (TT + 1) * D4 + tid;
    int s0 = 4 * i;

    float4 p0 = Pb[(size_t)(s0) * D4];
    float4 p1 = Pb[(size_t)(s0 + ws) * D4];
    float4 p2 = Pb[(size_t)(s0 + 2 * ws) * D4];
    float4 p3 = Pb[(size_t)(s0 + 3 * ws) * D4];
    float4 p4 = Pb[(size_t)(s0 + 4 * ws) * D4];

    fc_out[0 * D4 + tid] = diff_scale(p1, p0, sc);
    fc_out[1 * D4 + tid] = diff_scale(p2, p1, sc);
    fc_out[2 * D4 + tid] = diff_scale(p3, p2, sc);
    fc_out[3 * D4 + tid] = diff_scale(p4, p3, sc);
    fm_out[tid]          = diff_scale(p4, p0, sm);
}

// ---------------------------------------------------------------------------
// Kernel 3: fb[b,l,:] = mean of f over the 4 frames of segment l (float4).
// ---------------------------------------------------------------------------
__global__ __launch_bounds__(256) void fb_kernel(const float4* __restrict__ P4,
                                                 float4* __restrict__ fb4) {
    int idx = blockIdx.x * 256 + threadIdx.x;   // B*L*D4 = 131072 threads
    int d4 = idx & (D4 - 1);
    int l = (idx >> 7) & (LL - 1);
    int b = idx >> 12;
    const float4* Pb = P4 + (size_t)b * (TT + 1) * D4 + d4;
    float4 hi = Pb[(size_t)(4 * l + 4) * D4];
    float4 lo = Pb[(size_t)(4 * l) * D4];
    fb4[idx] = diff_scale(hi, lo, 0.25f);
}

// ---------------------------------------------------------------------------
// Fallback path (no workspace): direct window sums from f (L2/L3-resident).
// ---------------------------------------------------------------------------
__global__ __launch_bounds__(256) void fcfm_direct(const float* __restrict__ f,
                                                   const float* __restrict__ mask,
                                                   float* __restrict__ fc,
                                                   float* __restrict__ fm) {
    int blk = blockIdx.x;
    int j = blk & (LL - 1);
    int i = (blk >> 5) & (LL - 1);
    int b = blk >> 10;
    int tid = threadIdx.x;
    float* fc_out = fc + (size_t)blk * CC * DD;
    float* fm_out = fm + (size_t)blk * DD;

    if (j < i) {
        float4 z = make_float4(0.f, 0.f, 0.f, 0.f);
        float4* fc4 = (float4*)fc_out;
#pragma unroll
        for (int k = 0; k < 2; ++k) fc4[tid + k * 256] = z;
        float4* fm4 = (float4*)fm_out;
        if (tid < DD / 4) fm4[tid] = z;
        return;
    }

    int ws = j - i + 1;
    float m = mask[blk];
    float sc = m / (float)ws;
    const float* fbase = f + (size_t)b * TT * DD;

#pragma unroll
    for (int r = 0; r < 2; ++r) {
        int dd = tid + r * 256;
        float tot = 0.f;
#pragma unroll
        for (int c = 0; c < CC; ++c) {
            float s = 0.f;
            int t0 = 4 * i + c * ws;
            for (int t = 0; t < ws; ++t) s += fbase[(size_t)(t0 + t) * DD + dd];
            fc_out[c * DD + dd] = s * sc;
            tot += s;
        }
        fm_out[dd] = tot * sc * 0.25f;
    }
}

__global__ __launch_bounds__(256) void fb_direct(const float* __restrict__ f,
                                                 float* __restrict__ fb) {
    int idx = blockIdx.x * 256 + threadIdx.x;
    int d = idx & (DD - 1);
    int l = (idx >> 9) & (LL - 1);
    int b = idx >> 14;
    const float* fp = f + (size_t)b * TT * DD + d;
    int t0 = 4 * l;
    fb[idx] = (fp[(size_t)t0 * DD] + fp[(size_t)(t0 + 1) * DD] +
               fp[(size_t)(t0 + 2) * DD] + fp[(size_t)(t0 + 3) * DD]) * 0.25f;
}

extern "C" void kernel_launch(void* const* d_in, const int* in_sizes, int n_in,
                              void* d_out, int out_size, void* d_ws, size_t ws_size,
                              hipStream_t stream) {
    const float* f    = (const float*)d_in[0];   // [B,T,D]
    const float* mask = (const float*)d_in[1];   // [B,L,L]
    // d_in[2] = Wc, folded analytically (unused)

    float* out = (float*)d_out;
    const size_t fc_elems = (size_t)BB * LL * LL * CC * DD;   // 67,108,864
    const size_t fm_elems = (size_t)BB * LL * LL * DD;        // 16,777,216
    float* fc = out;
    float* fm = out + fc_elems;
    float* fb = out + fc_elems + fm_elems;

    const size_t P_bytes = (size_t)BB * (TT + 1) * DD * sizeof(float);  // ~8.45 MB

    if (ws_size >= P_bytes) {
        float* P = (float*)d_ws;
        prefix_kernel<<<(BB * DD) / 256, 256, 0, stream>>>(f, P);
        fcfm_kernel<<<BB * LL * LL, 128, 0, stream>>>((const float4*)P, mask,
                                                      (float4*)fc, (float4*)fm);
        fb_kernel<<<(BB * LL * D4) / 256, 256, 0, stream>>>((const float4*)P,
                                                            (float4*)fb);
    } else {
        fcfm_direct<<<BB * LL * LL, 256, 0, stream>>>(f, mask, fc, fm);
        fb_direct<<<(BB * LL * DD) / 256, 256, 0, stream>>>(f, fb);
    }
}